// Round 6
// baseline (960.154 us; speedup 1.0000x reference)
//
#include <hip/hip_runtime.h>

#define BB 64
#define LL 2048
#define TT 128

typedef float v4f __attribute__((ext_vector_type(4)));

__device__ __forceinline__ float rl(float v, int k) {
    return __uint_as_float(__builtin_amdgcn_readlane(__float_as_uint(v), k));
}

// ---------------- numerator: gold path score per batch ----------------
__global__ __launch_bounds__(256) void crf_num_kernel(
    const float* __restrict__ em, const int* __restrict__ tgt,
    const int* __restrict__ mask, const float* __restrict__ start,
    const float* __restrict__ endt, const float* __restrict__ trans,
    float* __restrict__ num_out)
{
    const int b = blockIdx.x;
    const int t = threadIdx.x;
    const int wave = t >> 6, lane = t & 63;
    const float* emb = em + (size_t)b * LL * TT;
    const int* tb = tgt + (size_t)b * LL;
    const int* mb = mask + (size_t)b * LL;

    float acc = 0.f;
    int msum = 0;
    for (int l = t; l < LL; l += 256) {
        int mv = mb[l];
        msum += mv;
        if (l >= 1 && mv > 0) {
            int tp = tb[l - 1], tc = tb[l];
            acc += trans[tp * TT + tc] + emb[(size_t)l * TT + tc];
        }
    }
    __shared__ float sacc[4];
    __shared__ int smsum[4];
    #pragma unroll
    for (int off = 32; off; off >>= 1) {
        acc += __shfl_xor(acc, off);
        msum += __shfl_xor(msum, off);
    }
    if (lane == 0) { sacc[wave] = acc; smsum[wave] = msum; }
    __syncthreads();
    if (t == 0) {
        float tot = sacc[0] + sacc[1] + sacc[2] + sacc[3];
        int total_mask = smsum[0] + smsum[1] + smsum[2] + smsum[3];
        int t0 = tb[0];
        tot += start[t0] + emb[t0];
        int se = total_mask - 1;
        int lt = tb[se];
        tot += endt[lt];
        num_out[b] = tot;
    }
}

// ---------------- denominator: forward algorithm, 1 block per batch ----------------
// Diagonal wave layout (4 waves), readlane broadcast (round 5, validated).
// NEW: raw s_barrier + manual lgkmcnt(0) instead of __syncthreads -> the
// compiler's vmcnt(0)-drain-at-barrier disappears, so the 8-deep emission
// prefetch actually stays in flight across steps (T4, counted vmcnt at use).
__global__ __launch_bounds__(256, 1) __attribute__((amdgpu_waves_per_eu(1, 2)))
void crf_forward_kernel(
    const float* __restrict__ em, const int* __restrict__ mask,
    const float* __restrict__ start, const float* __restrict__ endt,
    const float* __restrict__ trans, float* __restrict__ den_out)
{
    const int b = blockIdx.x;
    const int t = threadIdx.x;        // 0..255
    const int w = t >> 6;             // wave 0..3
    const int l = t & 63;             // lane
    const int jr   = w & 1;           // own j-range index
    const int tjr  = w >> 1;          // target j-range index
    const int jown = (jr  << 6) + l;  // own tag (s, em, start, end)
    const int jtgt = (tjr << 6) + l;  // target column (E, partial)
    const int kbase = jr << 6;        // k-chunk base (= own range)

    __shared__ float partial_sh[2][2][2][64];  // [buf][tjr][khalf][lane]
    __shared__ float s0_sh[2];                 // lag offset slots
    __shared__ int   mask_sh[LL];
    __shared__ float red[4], red2[4];

    const float* emb = em + (size_t)b * LL * TT;
    const int* mb = mask + (size_t)b * LL;

    for (int x = t; x < LL; x += 256) mask_sh[x] = mb[x];

    // cjE: normalizer for E block (target column); cjS: for own column update
    float cjE = -1e30f, cjS = -1e30f;
    for (int k = 0; k < TT; ++k) {
        cjE = fmaxf(cjE, trans[k * TT + jtgt]);
        cjS = fmaxf(cjS, trans[k * TT + jown]);
    }

#define EINIT(n) const v4f E##n = { \
    __expf(trans[(kbase + 4*(n) + 0) * TT + jtgt] - cjE), \
    __expf(trans[(kbase + 4*(n) + 1) * TT + jtgt] - cjE), \
    __expf(trans[(kbase + 4*(n) + 2) * TT + jtgt] - cjE), \
    __expf(trans[(kbase + 4*(n) + 3) * TT + jtgt] - cjE) };
    EINIT(0)  EINIT(1)  EINIT(2)  EINIT(3)
    EINIT(4)  EINIT(5)  EINIT(6)  EINIT(7)
    EINIT(8)  EINIT(9)  EINIT(10) EINIT(11)
    EINIT(12) EINIT(13) EINIT(14) EINIT(15)
#undef EINIT

    float s = start[jown] + emb[jown];
    if (t == 0) { s0_sh[0] = s; s0_sh[1] = s; }   // seed both lag slots with s_0[0]
    __syncthreads();                               // one-time full barrier (prologue)
    float m_reg = s0_sh[0];

    // 8-deep rolling prefetch of emission values for OWN tag
    float e0 = emb[(size_t)1 * TT + jown];
    float e1 = emb[(size_t)2 * TT + jown];
    float e2 = emb[(size_t)3 * TT + jown];
    float e3 = emb[(size_t)4 * TT + jown];
    float e4 = emb[(size_t)5 * TT + jown];
    float e5 = emb[(size_t)6 * TT + jown];
    float e6 = emb[(size_t)7 * TT + jown];
    float e7 = emb[(size_t)8 * TT + jown];

    for (int i = 1; i < LL; ++i) {
        const float em_cur = e0;
        e0 = e1; e1 = e2; e2 = e3; e3 = e4; e4 = e5; e5 = e6; e6 = e7;
        if (i + 8 < LL) e7 = emb[(size_t)(i + 8) * TT + jown];

        const float p = __expf(s - m_reg);         // local: own tag's p

        // partial[jtgt] = sum_{k in own chunk} p[k] * E[k][jtgt]
        float a0 = 0.f, a1 = 0.f, a2 = 0.f, a3 = 0.f;
#define FMA4(n) \
        a0 = fmaf(rl(p, 4*(n)+0), E##n.x, a0); \
        a1 = fmaf(rl(p, 4*(n)+1), E##n.y, a1); \
        a2 = fmaf(rl(p, 4*(n)+2), E##n.z, a2); \
        a3 = fmaf(rl(p, 4*(n)+3), E##n.w, a3);
        FMA4(0)  FMA4(1)  FMA4(2)  FMA4(3)
        FMA4(4)  FMA4(5)  FMA4(6)  FMA4(7)
        FMA4(8)  FMA4(9)  FMA4(10) FMA4(11)
        FMA4(12) FMA4(13) FMA4(14) FMA4(15)
#undef FMA4
        const float partial = (a0 + a2) + (a1 + a3);

        const int buf = i & 1;
        partial_sh[buf][tjr][jr][l] = partial;     // jr == k-half index here
        if (t == 0) s0_sh[buf] = s;                // s_{i-1}[0] -> m for step i+1

        // raw barrier: LDS drained, global prefetch stays in flight (no vmcnt(0))
        asm volatile("s_waitcnt lgkmcnt(0)" ::: "memory");
        __builtin_amdgcn_s_barrier();
        asm volatile("" ::: "memory");

        const float pa = partial_sh[buf][jr][0][l];
        const float pb = partial_sh[buf][jr][1][l];
        const float mnext = s0_sh[buf];
        const float acc = pa + pb;

        const float snew = em_cur + m_reg + cjS + __logf(acc);
        s = (mask_sh[i] > 0) ? snew : s;
        m_reg = mnext;
    }

    // den = logsumexp_j(s[j] + end[j]); waves 0,1 cover all tags, 2,3 duplicate
    float v = s + endt[jown];
    float m2 = v;
    #pragma unroll
    for (int off = 32; off; off >>= 1) m2 = fmaxf(m2, __shfl_xor(m2, off));
    if (l == 0) red2[w] = m2;
    __syncthreads();
    m2 = fmaxf(fmaxf(red2[0], red2[1]), fmaxf(red2[2], red2[3]));
    float e = (w < 2) ? __expf(v - m2) : 0.f;      // count each tag once
    #pragma unroll
    for (int off = 32; off; off >>= 1) e += __shfl_xor(e, off);
    if (l == 0) red[w] = e;
    __syncthreads();
    if (t == 0) den_out[b] = m2 + __logf(red[0] + red[1] + red[2] + red[3]);
}

// ---------------- final: out = sum_b (den_b - num_b) ----------------
__global__ void crf_final_kernel(const float* __restrict__ den,
                                 const float* __restrict__ num,
                                 float* __restrict__ out)
{
    int t = threadIdx.x;   // 64 threads == BB
    float v = den[t] - num[t];
    #pragma unroll
    for (int off = 32; off; off >>= 1) v += __shfl_xor(v, off);
    if (t == 0) out[0] = v;
}

extern "C" void kernel_launch(void* const* d_in, const int* in_sizes, int n_in,
                              void* d_out, int out_size, void* d_ws, size_t ws_size,
                              hipStream_t stream)
{
    const float* em    = (const float*)d_in[0];   // [B,L,T] f32
    const int*   tgt   = (const int*)d_in[1];     // [B,L]
    const int*   mask  = (const int*)d_in[2];     // [B,L]
    const float* start = (const float*)d_in[3];   // [T]
    const float* endt  = (const float*)d_in[4];   // [T]
    const float* trans = (const float*)d_in[5];   // [T,T]
    float* out = (float*)d_out;

    float* den = (float*)d_ws;        // BB floats
    float* num = den + BB;            // BB floats

    crf_num_kernel<<<BB, 256, 0, stream>>>(em, tgt, mask, start, endt, trans, num);
    crf_forward_kernel<<<BB, 256, 0, stream>>>(em, mask, start, endt, trans, den);
    crf_final_kernel<<<1, 64, 0, stream>>>(den, num, out);
}

// Round 8
// 58.966 us; speedup vs baseline: 16.2833x; 16.2833x over previous
//
#include <hip/hip_runtime.h>

#define BB 64
#define LL 2048
#define TT 128

// ws layout (floats): den[0..63] num[64..127] t0[128] flag(u32 @129) r[256 ..]
#define WS_NEED ((256 + BB * LL) * 4)

// ---------------- uniformity checker: flag=1 iff all trans entries identical ----------------
__global__ __launch_bounds__(256) void crf_check_kernel(
    const float* __restrict__ trans, unsigned* __restrict__ flag,
    float* __restrict__ t0out)
{
    __shared__ int ok_sh;
    if (threadIdx.x == 0) ok_sh = 1;
    __syncthreads();
    const unsigned t0 = __float_as_uint(trans[0]);
    int ok = 1;
    for (int i = threadIdx.x; i < TT * TT; i += 256)
        ok &= (__float_as_uint(trans[i]) == t0);
    if (!ok) atomicAnd(&ok_sh, 0);
    __syncthreads();
    if (threadIdx.x == 0) { *flag = (unsigned)ok_sh; *t0out = __uint_as_float(t0); }
}

// ---------------- numerator: gold path score per batch ----------------
__global__ __launch_bounds__(256) void crf_num_kernel(
    const float* __restrict__ em, const int* __restrict__ tgt,
    const int* __restrict__ mask, const float* __restrict__ start,
    const float* __restrict__ endt, const float* __restrict__ trans,
    float* __restrict__ num_out)
{
    const int b = blockIdx.x;
    const int t = threadIdx.x;
    const int wave = t >> 6, lane = t & 63;
    const float* emb = em + (size_t)b * LL * TT;
    const int* tb = tgt + (size_t)b * LL;
    const int* mb = mask + (size_t)b * LL;

    float acc = 0.f;
    int msum = 0;
    for (int l = t; l < LL; l += 256) {
        int mv = mb[l];
        msum += mv;
        if (l >= 1 && mv > 0) {
            int tp = tb[l - 1], tc = tb[l];
            acc += trans[tp * TT + tc] + emb[(size_t)l * TT + tc];
        }
    }
    __shared__ float sacc[4];
    __shared__ int smsum[4];
    #pragma unroll
    for (int off = 32; off; off >>= 1) {
        acc += __shfl_xor(acc, off);
        msum += __shfl_xor(msum, off);
    }
    if (lane == 0) { sacc[wave] = acc; smsum[wave] = msum; }
    __syncthreads();
    if (t == 0) {
        float tot = sacc[0] + sacc[1] + sacc[2] + sacc[3];
        int total_mask = smsum[0] + smsum[1] + smsum[2] + smsum[3];
        int t0 = tb[0];
        tot += start[t0] + emb[t0];
        int se = total_mask - 1;
        int lt = tb[se];
        tot += endt[lt];
        num_out[b] = tot;
    }
}

// ---------------- fast path A: per-row logsumexp over tags (fully parallel) ----------------
// One wave per row; lane holds em[row][lane] and em[row][lane+64].
__global__ __launch_bounds__(256) void crf_rowlse_kernel(
    const float* __restrict__ em, const unsigned* __restrict__ flag,
    float* __restrict__ r)
{
    if (*flag == 0) return;
    const int row = blockIdx.x * 4 + (threadIdx.x >> 6);   // 0 .. BB*LL-1
    const int lane = threadIdx.x & 63;
    const float* p = em + (size_t)row * TT;
    const float a = p[lane];
    const float c = p[lane + 64];
    float mx = fmaxf(a, c);
    #pragma unroll
    for (int off = 32; off; off >>= 1) mx = fmaxf(mx, __shfl_xor(mx, off));
    float s = __expf(a - mx) + __expf(c - mx);
    #pragma unroll
    for (int off = 32; off; off >>= 1) s += __shfl_xor(s, off);
    if (lane == 0) r[row] = mx + __logf(s);
}

// ---------------- fast path B: per-batch combine ----------------
// den_b = lse(start+em0) + K*t0 + sum_{active i != last} r[i] + lse(em_last+end)
// (K = #active steps i>=1; if K==0: den = lse(start+em0+end))
__global__ __launch_bounds__(256) void crf_combine_kernel(
    const float* __restrict__ em, const int* __restrict__ mask,
    const float* __restrict__ start, const float* __restrict__ endt,
    const unsigned* __restrict__ flag, const float* __restrict__ t0p,
    const float* __restrict__ r, float* __restrict__ den_out)
{
    if (*flag == 0) return;
    const int b = blockIdx.x;
    const int t = threadIdx.x;
    const int wave = t >> 6, lane = t & 63;
    const int* mb = mask + (size_t)b * LL;
    const float* rb = r + (size_t)b * LL;
    const float* emb = em + (size_t)b * LL * TT;

    __shared__ float s_rs[4];
    __shared__ int s_k[4], s_last[4];
    __shared__ int g_k, g_last;
    __shared__ float g_rs;
    __shared__ float s_max[4], s_sum[4];

    int k = 0, last = 0;
    float rs = 0.f;
    for (int i = t; i < LL; i += 256) {
        const int mv = (i >= 1) ? mb[i] : 0;
        if (mv > 0) { ++k; last = (i > last) ? i : last; rs += rb[i]; }
    }
    #pragma unroll
    for (int off = 32; off; off >>= 1) {
        k += __shfl_xor(k, off);
        last = max(last, __shfl_xor(last, off));
        rs += __shfl_xor(rs, off);
    }
    if (lane == 0) { s_k[wave] = k; s_last[wave] = last; s_rs[wave] = rs; }
    __syncthreads();
    if (t == 0) {
        g_k = s_k[0] + s_k[1] + s_k[2] + s_k[3];
        g_last = max(max(s_last[0], s_last[1]), max(s_last[2], s_last[3]));
        g_rs = s_rs[0] + s_rs[1] + s_rs[2] + s_rs[3];
    }
    __syncthreads();
    const int K = g_k;
    const int lastI = g_last;

    // waves 0,1: lse(start+em0 [+end if K==0]);  waves 2,3: lse(em_last+end)
    float x;
    if (t < 128) {
        x = start[t] + emb[t] + ((K == 0) ? endt[t] : 0.f);
    } else {
        const int j = t - 128;
        x = (K > 0) ? (emb[(size_t)lastI * TT + j] + endt[j]) : -1e30f;
    }
    float mx = x;
    #pragma unroll
    for (int off = 32; off; off >>= 1) mx = fmaxf(mx, __shfl_xor(mx, off));
    if (lane == 0) s_max[wave] = mx;
    __syncthreads();
    const float m01 = fmaxf(s_max[0], s_max[1]);
    const float m23 = fmaxf(s_max[2], s_max[3]);
    float e = __expf(x - ((t < 128) ? m01 : m23));
    #pragma unroll
    for (int off = 32; off; off >>= 1) e += __shfl_xor(e, off);
    if (lane == 0) s_sum[wave] = e;
    __syncthreads();
    if (t == 0) {
        const float lse0 = m01 + __logf(s_sum[0] + s_sum[1]);
        if (K == 0) {
            den_out[b] = lse0;
        } else {
            const float lseE = m23 + __logf(s_sum[2] + s_sum[3]);
            const float t0 = *t0p;
            den_out[b] = lse0 + (float)K * t0 + (g_rs - rb[lastI]) + lseE;
        }
    }
}

// ---------------- general fallback: forward scan (round-6, validated) ----------------
typedef float v4f __attribute__((ext_vector_type(4)));
__device__ __forceinline__ float rl(float v, int k) {
    return __uint_as_float((unsigned)__builtin_amdgcn_readlane((int)__float_as_uint(v), k));
}

__global__ __launch_bounds__(256, 1) __attribute__((amdgpu_waves_per_eu(1, 2)))
void crf_forward_kernel(
    const float* __restrict__ em, const int* __restrict__ mask,
    const float* __restrict__ start, const float* __restrict__ endt,
    const float* __restrict__ trans, float* __restrict__ den_out,
    const unsigned* __restrict__ uflag)
{
    if (uflag && *uflag != 0) return;    // uniform trans handled by fast path

    const int b = blockIdx.x;
    const int t = threadIdx.x;
    const int w = t >> 6;
    const int l = t & 63;
    const int jr   = w & 1;
    const int tjr  = w >> 1;
    const int jown = (jr  << 6) + l;
    const int jtgt = (tjr << 6) + l;
    const int kbase = jr << 6;

    __shared__ float partial_sh[2][2][2][64];
    __shared__ float s0_sh[2];
    __shared__ int   mask_sh[LL];
    __shared__ float red[4], red2[4];

    const float* emb = em + (size_t)b * LL * TT;
    const int* mb = mask + (size_t)b * LL;

    for (int x = t; x < LL; x += 256) mask_sh[x] = mb[x];

    float cjE = -1e30f, cjS = -1e30f;
    for (int k = 0; k < TT; ++k) {
        cjE = fmaxf(cjE, trans[k * TT + jtgt]);
        cjS = fmaxf(cjS, trans[k * TT + jown]);
    }

#define EINIT(n) const v4f E##n = { \
    __expf(trans[(kbase + 4*(n) + 0) * TT + jtgt] - cjE), \
    __expf(trans[(kbase + 4*(n) + 1) * TT + jtgt] - cjE), \
    __expf(trans[(kbase + 4*(n) + 2) * TT + jtgt] - cjE), \
    __expf(trans[(kbase + 4*(n) + 3) * TT + jtgt] - cjE) };
    EINIT(0)  EINIT(1)  EINIT(2)  EINIT(3)
    EINIT(4)  EINIT(5)  EINIT(6)  EINIT(7)
    EINIT(8)  EINIT(9)  EINIT(10) EINIT(11)
    EINIT(12) EINIT(13) EINIT(14) EINIT(15)
#undef EINIT

    float s = start[jown] + emb[jown];
    if (t == 0) { s0_sh[0] = s; s0_sh[1] = s; }
    __syncthreads();
    float m_reg = s0_sh[0];

    float e0 = emb[(size_t)1 * TT + jown];
    float e1 = emb[(size_t)2 * TT + jown];
    float e2 = emb[(size_t)3 * TT + jown];
    float e3 = emb[(size_t)4 * TT + jown];
    float e4 = emb[(size_t)5 * TT + jown];
    float e5 = emb[(size_t)6 * TT + jown];
    float e6 = emb[(size_t)7 * TT + jown];
    float e7 = emb[(size_t)8 * TT + jown];

    for (int i = 1; i < LL; ++i) {
        const float em_cur = e0;
        e0 = e1; e1 = e2; e2 = e3; e3 = e4; e4 = e5; e5 = e6; e6 = e7;
        if (i + 8 < LL) e7 = emb[(size_t)(i + 8) * TT + jown];

        const float p = __expf(s - m_reg);

        float a0 = 0.f, a1 = 0.f, a2 = 0.f, a3 = 0.f;
#define FMA4(n) \
        a0 = fmaf(rl(p, 4*(n)+0), E##n.x, a0); \
        a1 = fmaf(rl(p, 4*(n)+1), E##n.y, a1); \
        a2 = fmaf(rl(p, 4*(n)+2), E##n.z, a2); \
        a3 = fmaf(rl(p, 4*(n)+3), E##n.w, a3);
        FMA4(0)  FMA4(1)  FMA4(2)  FMA4(3)
        FMA4(4)  FMA4(5)  FMA4(6)  FMA4(7)
        FMA4(8)  FMA4(9)  FMA4(10) FMA4(11)
        FMA4(12) FMA4(13) FMA4(14) FMA4(15)
#undef FMA4
        const float partial = (a0 + a2) + (a1 + a3);

        const int buf = i & 1;
        partial_sh[buf][tjr][jr][l] = partial;
        if (t == 0) s0_sh[buf] = s;

        asm volatile("s_waitcnt lgkmcnt(0)" ::: "memory");
        __builtin_amdgcn_s_barrier();
        asm volatile("" ::: "memory");

        const float pa = partial_sh[buf][jr][0][l];
        const float pb = partial_sh[buf][jr][1][l];
        const float mnext = s0_sh[buf];
        const float acc = pa + pb;

        const float snew = em_cur + m_reg + cjS + __logf(acc);
        s = (mask_sh[i] > 0) ? snew : s;
        m_reg = mnext;
    }

    float v = s + endt[jown];
    float m2 = v;
    #pragma unroll
    for (int off = 32; off; off >>= 1) m2 = fmaxf(m2, __shfl_xor(m2, off));
    if (l == 0) red2[w] = m2;
    __syncthreads();
    m2 = fmaxf(fmaxf(red2[0], red2[1]), fmaxf(red2[2], red2[3]));
    float e = (w < 2) ? __expf(v - m2) : 0.f;
    #pragma unroll
    for (int off = 32; off; off >>= 1) e += __shfl_xor(e, off);
    if (l == 0) red[w] = e;
    __syncthreads();
    if (t == 0) den_out[b] = m2 + __logf(red[0] + red[1] + red[2] + red[3]);
}

// ---------------- final: out = sum_b (den_b - num_b) ----------------
__global__ void crf_final_kernel(const float* __restrict__ den,
                                 const float* __restrict__ num,
                                 float* __restrict__ out)
{
    int t = threadIdx.x;   // 64 threads == BB
    float v = den[t] - num[t];
    #pragma unroll
    for (int off = 32; off; off >>= 1) v += __shfl_xor(v, off);
    if (t == 0) out[0] = v;
}

extern "C" void kernel_launch(void* const* d_in, const int* in_sizes, int n_in,
                              void* d_out, int out_size, void* d_ws, size_t ws_size,
                              hipStream_t stream)
{
    const float* em    = (const float*)d_in[0];   // [B,L,T] f32
    const int*   tgt   = (const int*)d_in[1];     // [B,L]
    const int*   mask  = (const int*)d_in[2];     // [B,L]
    const float* start = (const float*)d_in[3];   // [T]
    const float* endt  = (const float*)d_in[4];   // [T]
    const float* trans = (const float*)d_in[5];   // [T,T]
    float* out = (float*)d_out;

    float*    den  = (float*)d_ws;            // [64]
    float*    num  = den + BB;                // [64]
    float*    t0p  = den + 128;               // [1]
    unsigned* flag = (unsigned*)(den + 129);  // [1]
    float*    r    = den + 256;               // [BB*LL]

    if (ws_size >= (size_t)WS_NEED) {
        crf_check_kernel<<<1, 256, 0, stream>>>(trans, flag, t0p);
        crf_num_kernel<<<BB, 256, 0, stream>>>(em, tgt, mask, start, endt, trans, num);
        crf_rowlse_kernel<<<(BB * LL) / 4, 256, 0, stream>>>(em, flag, r);
        crf_combine_kernel<<<BB, 256, 0, stream>>>(em, mask, start, endt, flag, t0p, r, den);
        crf_forward_kernel<<<BB, 256, 0, stream>>>(em, mask, start, endt, trans, den, flag);
        crf_final_kernel<<<1, 64, 0, stream>>>(den, num, out);
    } else {
        crf_num_kernel<<<BB, 256, 0, stream>>>(em, tgt, mask, start, endt, trans, num);
        crf_forward_kernel<<<BB, 256, 0, stream>>>(em, mask, start, endt, trans, den, nullptr);
        crf_final_kernel<<<1, 64, 0, stream>>>(den, num, out);
    }
}

// Round 9
// 30.884 us; speedup vs baseline: 31.0891x; 1.9093x over previous
//
#include <hip/hip_runtime.h>

#define BB 64
#define LL 2048
#define TT 128
#define NROWS (BB * LL)

// ws layout (4B units): den[0..63] num[64..127] okpart[128..191] (u32)
//                       r[256 .. 256+NROWS) etag[256+NROWS .. 256+2*NROWS)
#define WS_NEED ((256 + 2 * NROWS) * 4)

// ---------------- fused: per-row lse + gold-tag gather + trans uniformity check ----
// 256 thr = 4 waves; wave = 2 rows (float4/lane). Blocks 0..63 also check a
// 256-entry slice of trans and write okpart[block].
__global__ __launch_bounds__(256) void crf_rowlse_kernel(
    const float* __restrict__ em, const int* __restrict__ tgt,
    const float* __restrict__ trans,
    float* __restrict__ r, float* __restrict__ etag,
    unsigned* __restrict__ okpart)
{
    const int t = threadIdx.x;
    const int wave = t >> 6, l = t & 63;
    const int h = l >> 5;                       // half-wave
    const int wv = blockIdx.x * 4 + wave;       // global wave id
    const int row = wv * 2 + h;                 // row handled by this half

    // trans uniformity check (first 64 blocks cover all 16384 entries)
    __shared__ int oksh[4];
    if (blockIdx.x < 64) {
        const unsigned t0b = __float_as_uint(trans[0]);
        const int ok = (__float_as_uint(trans[blockIdx.x * 256 + t]) == t0b);
        const int wok = __all(ok);
        if (l == 0) oksh[wave] = wok;
        __syncthreads();
        if (t == 0) okpart[blockIdx.x] = (unsigned)(oksh[0] & oksh[1] & oksh[2] & oksh[3]);
    }

    // row lse (float4: lanes 0-31 row, lanes 32-63 row+1)
    const float4 v = *(const float4*)(em + (size_t)wv * 256 + l * 4);
    float mx = fmaxf(fmaxf(v.x, v.y), fmaxf(v.z, v.w));
    #pragma unroll
    for (int off = 16; off; off >>= 1) mx = fmaxf(mx, __shfl_xor(mx, off));
    float s = __expf(v.x - mx) + __expf(v.y - mx) + __expf(v.z - mx) + __expf(v.w - mx);
    #pragma unroll
    for (int off = 16; off; off >>= 1) s += __shfl_xor(s, off);

    // gold-tag gather: etag[row] = em[row][tg]
    const int tg = tgt[row];                    // uniform within half-wave
    const float c01 = (tg & 1) ? v.y : v.x;
    const float c23 = (tg & 1) ? v.w : v.z;
    const float cand = (tg & 2) ? c23 : c01;
    const float ev = __shfl(cand, (h << 5) + (tg >> 2));

    if ((l & 31) == 0) {
        r[row] = mx + __logf(s);
        etag[row] = ev;
    }
}

// ---------------- combine (uniform path): den_b AND num_b ----------------
__global__ __launch_bounds__(256) void crf_combine_kernel(
    const float* __restrict__ em, const int* __restrict__ tgt,
    const int* __restrict__ mask, const float* __restrict__ start,
    const float* __restrict__ endt, const float* __restrict__ trans,
    const unsigned* __restrict__ okpart, const float* __restrict__ r,
    const float* __restrict__ etag,
    float* __restrict__ den_out, float* __restrict__ num_out)
{
    const int t = threadIdx.x;
    const int wave = t >> 6, lane = t & 63;
    __shared__ int fsh[4];
    {
        const int myok = (t < 64) ? (int)okpart[t] : 1;
        const int wok = __all(myok);
        if (lane == 0) fsh[wave] = wok;
        __syncthreads();
        if (!(fsh[0] & fsh[1] & fsh[2] & fsh[3])) return;   // general path handles it
    }

    const int b = blockIdx.x;
    const int* mb = mask + (size_t)b * LL;
    const float* rb = r + (size_t)b * LL;
    const float* eb = etag + (size_t)b * LL;
    const float* emb = em + (size_t)b * LL * TT;

    __shared__ float s_rs[4], s_es[4];
    __shared__ int s_k[4], s_last[4];
    __shared__ int g_k, g_last;
    __shared__ float g_rs, g_es;
    __shared__ float s_max[4], s_sum[4];

    int k = 0, last = 0;
    float rs = 0.f, es = 0.f;
    for (int i = t; i < LL; i += 256) {
        const int mv = (i >= 1) ? mb[i] : 0;
        if (mv > 0) { ++k; last = (i > last) ? i : last; rs += rb[i]; es += eb[i]; }
    }
    #pragma unroll
    for (int off = 32; off; off >>= 1) {
        k += __shfl_xor(k, off);
        last = max(last, __shfl_xor(last, off));
        rs += __shfl_xor(rs, off);
        es += __shfl_xor(es, off);
    }
    if (lane == 0) { s_k[wave] = k; s_last[wave] = last; s_rs[wave] = rs; s_es[wave] = es; }
    __syncthreads();
    if (t == 0) {
        g_k = s_k[0] + s_k[1] + s_k[2] + s_k[3];
        g_last = max(max(s_last[0], s_last[1]), max(s_last[2], s_last[3]));
        g_rs = s_rs[0] + s_rs[1] + s_rs[2] + s_rs[3];
        g_es = s_es[0] + s_es[1] + s_es[2] + s_es[3];
    }
    __syncthreads();
    const int K = g_k;
    const int lastI = g_last;

    // waves 0,1: lse(start+em0 [+end if K==0]); waves 2,3: lse(em_last+end)
    float x;
    if (t < 128) {
        x = start[t] + emb[t] + ((K == 0) ? endt[t] : 0.f);
    } else {
        const int j = t - 128;
        x = (K > 0) ? (emb[(size_t)lastI * TT + j] + endt[j]) : -1e30f;
    }
    float mx = x;
    #pragma unroll
    for (int off = 32; off; off >>= 1) mx = fmaxf(mx, __shfl_xor(mx, off));
    if (lane == 0) s_max[wave] = mx;
    __syncthreads();
    const float m01 = fmaxf(s_max[0], s_max[1]);
    const float m23 = fmaxf(s_max[2], s_max[3]);
    float e = __expf(x - ((t < 128) ? m01 : m23));
    #pragma unroll
    for (int off = 32; off; off >>= 1) e += __shfl_xor(e, off);
    if (lane == 0) s_sum[wave] = e;
    __syncthreads();
    if (t == 0) {
        const float t0 = trans[0];
        const int tg0 = tgt[(size_t)b * LL];
        const float et0 = eb[0];
        const float lse0 = m01 + __logf(s_sum[0] + s_sum[1]);
        if (K == 0) {
            den_out[b] = lse0;
            num_out[b] = start[tg0] + et0 + endt[tg0];
        } else {
            const float lseE = m23 + __logf(s_sum[2] + s_sum[3]);
            den_out[b] = lse0 + (float)K * t0 + (g_rs - rb[lastI]) + lseE;
            const int tgl = tgt[(size_t)b * LL + K];   // seq_ends = sum(mask)-1 = K
            num_out[b] = start[tg0] + et0 + (float)K * t0 + g_es + endt[tgl];
        }
    }
}

// ---------------- general numerator (gated: runs only if trans non-uniform) ----
__global__ __launch_bounds__(256) void crf_num_kernel(
    const float* __restrict__ em, const int* __restrict__ tgt,
    const int* __restrict__ mask, const float* __restrict__ start,
    const float* __restrict__ endt, const float* __restrict__ trans,
    float* __restrict__ num_out, const unsigned* __restrict__ okpart)
{
    const int t = threadIdx.x;
    const int wave = t >> 6, lane = t & 63;
    __shared__ int fsh[4];
    if (okpart) {
        const int myok = (t < 64) ? (int)okpart[t] : 1;
        const int wok = __all(myok);
        if (lane == 0) fsh[wave] = wok;
        __syncthreads();
        if (fsh[0] & fsh[1] & fsh[2] & fsh[3]) return;   // uniform -> combine did it
        __syncthreads();
    }

    const int b = blockIdx.x;
    const float* emb = em + (size_t)b * LL * TT;
    const int* tb = tgt + (size_t)b * LL;
    const int* mb = mask + (size_t)b * LL;

    float acc = 0.f;
    int msum = 0;
    for (int l = t; l < LL; l += 256) {
        int mv = mb[l];
        msum += mv;
        if (l >= 1 && mv > 0) {
            int tp = tb[l - 1], tc = tb[l];
            acc += trans[tp * TT + tc] + emb[(size_t)l * TT + tc];
        }
    }
    __shared__ float sacc[4];
    __shared__ int smsum[4];
    #pragma unroll
    for (int off = 32; off; off >>= 1) {
        acc += __shfl_xor(acc, off);
        msum += __shfl_xor(msum, off);
    }
    if (lane == 0) { sacc[wave] = acc; smsum[wave] = msum; }
    __syncthreads();
    if (t == 0) {
        float tot = sacc[0] + sacc[1] + sacc[2] + sacc[3];
        int total_mask = smsum[0] + smsum[1] + smsum[2] + smsum[3];
        int t0 = tb[0];
        tot += start[t0] + emb[t0];
        int se = total_mask - 1;
        int lt = tb[se];
        tot += endt[lt];
        num_out[b] = tot;
    }
}

// ---------------- general forward scan (gated; round-6 validated core) ----------
typedef float v4f __attribute__((ext_vector_type(4)));
__device__ __forceinline__ float rl(float v, int k) {
    return __uint_as_float((unsigned)__builtin_amdgcn_readlane((int)__float_as_uint(v), k));
}

__global__ __launch_bounds__(256, 1) __attribute__((amdgpu_waves_per_eu(1, 2)))
void crf_forward_kernel(
    const float* __restrict__ em, const int* __restrict__ mask,
    const float* __restrict__ start, const float* __restrict__ endt,
    const float* __restrict__ trans, float* __restrict__ den_out,
    const unsigned* __restrict__ okpart)
{
    const int t = threadIdx.x;
    const int w = t >> 6;
    const int l = t & 63;
    __shared__ int fsh[4];
    if (okpart) {
        const int myok = (t < 64) ? (int)okpart[t] : 1;
        const int wok = __all(myok);
        if (l == 0) fsh[w] = wok;
        __syncthreads();
        if (fsh[0] & fsh[1] & fsh[2] & fsh[3]) return;   // uniform -> fast path did it
        __syncthreads();
    }

    const int b = blockIdx.x;
    const int jr   = w & 1;
    const int tjr  = w >> 1;
    const int jown = (jr  << 6) + l;
    const int jtgt = (tjr << 6) + l;
    const int kbase = jr << 6;

    __shared__ float partial_sh[2][2][2][64];
    __shared__ float s0_sh[2];
    __shared__ int   mask_sh[LL];
    __shared__ float red[4], red2[4];

    const float* emb = em + (size_t)b * LL * TT;
    const int* mb = mask + (size_t)b * LL;

    for (int x = t; x < LL; x += 256) mask_sh[x] = mb[x];

    float cjE = -1e30f, cjS = -1e30f;
    for (int k = 0; k < TT; ++k) {
        cjE = fmaxf(cjE, trans[k * TT + jtgt]);
        cjS = fmaxf(cjS, trans[k * TT + jown]);
    }

#define EINIT(n) const v4f E##n = { \
    __expf(trans[(kbase + 4*(n) + 0) * TT + jtgt] - cjE), \
    __expf(trans[(kbase + 4*(n) + 1) * TT + jtgt] - cjE), \
    __expf(trans[(kbase + 4*(n) + 2) * TT + jtgt] - cjE), \
    __expf(trans[(kbase + 4*(n) + 3) * TT + jtgt] - cjE) };
    EINIT(0)  EINIT(1)  EINIT(2)  EINIT(3)
    EINIT(4)  EINIT(5)  EINIT(6)  EINIT(7)
    EINIT(8)  EINIT(9)  EINIT(10) EINIT(11)
    EINIT(12) EINIT(13) EINIT(14) EINIT(15)
#undef EINIT

    float s = start[jown] + emb[jown];
    if (t == 0) { s0_sh[0] = s; s0_sh[1] = s; }
    __syncthreads();
    float m_reg = s0_sh[0];

    float e0 = emb[(size_t)1 * TT + jown];
    float e1 = emb[(size_t)2 * TT + jown];
    float e2 = emb[(size_t)3 * TT + jown];
    float e3 = emb[(size_t)4 * TT + jown];
    float e4 = emb[(size_t)5 * TT + jown];
    float e5 = emb[(size_t)6 * TT + jown];
    float e6 = emb[(size_t)7 * TT + jown];
    float e7 = emb[(size_t)8 * TT + jown];

    for (int i = 1; i < LL; ++i) {
        const float em_cur = e0;
        e0 = e1; e1 = e2; e2 = e3; e3 = e4; e4 = e5; e5 = e6; e6 = e7;
        if (i + 8 < LL) e7 = emb[(size_t)(i + 8) * TT + jown];

        const float p = __expf(s - m_reg);

        float a0 = 0.f, a1 = 0.f, a2 = 0.f, a3 = 0.f;
#define FMA4(n) \
        a0 = fmaf(rl(p, 4*(n)+0), E##n.x, a0); \
        a1 = fmaf(rl(p, 4*(n)+1), E##n.y, a1); \
        a2 = fmaf(rl(p, 4*(n)+2), E##n.z, a2); \
        a3 = fmaf(rl(p, 4*(n)+3), E##n.w, a3);
        FMA4(0)  FMA4(1)  FMA4(2)  FMA4(3)
        FMA4(4)  FMA4(5)  FMA4(6)  FMA4(7)
        FMA4(8)  FMA4(9)  FMA4(10) FMA4(11)
        FMA4(12) FMA4(13) FMA4(14) FMA4(15)
#undef FMA4
        const float partial = (a0 + a2) + (a1 + a3);

        const int buf = i & 1;
        partial_sh[buf][tjr][jr][l] = partial;
        if (t == 0) s0_sh[buf] = s;

        asm volatile("s_waitcnt lgkmcnt(0)" ::: "memory");
        __builtin_amdgcn_s_barrier();
        asm volatile("" ::: "memory");

        const float pa = partial_sh[buf][jr][0][l];
        const float pb = partial_sh[buf][jr][1][l];
        const float mnext = s0_sh[buf];
        const float acc = pa + pb;

        const float snew = em_cur + m_reg + cjS + __logf(acc);
        s = (mask_sh[i] > 0) ? snew : s;
        m_reg = mnext;
    }

    float v = s + endt[jown];
    float m2 = v;
    #pragma unroll
    for (int off = 32; off; off >>= 1) m2 = fmaxf(m2, __shfl_xor(m2, off));
    if (l == 0) red2[w] = m2;
    __syncthreads();
    m2 = fmaxf(fmaxf(red2[0], red2[1]), fmaxf(red2[2], red2[3]));
    float e = (w < 2) ? __expf(v - m2) : 0.f;
    #pragma unroll
    for (int off = 32; off; off >>= 1) e += __shfl_xor(e, off);
    if (l == 0) red[w] = e;
    __syncthreads();
    if (t == 0) den_out[b] = m2 + __logf(red[0] + red[1] + red[2] + red[3]);
}

// ---------------- final: out = sum_b (den_b - num_b) ----------------
__global__ void crf_final_kernel(const float* __restrict__ den,
                                 const float* __restrict__ num,
                                 float* __restrict__ out)
{
    int t = threadIdx.x;   // 64 threads == BB
    float v = den[t] - num[t];
    #pragma unroll
    for (int off = 32; off; off >>= 1) v += __shfl_xor(v, off);
    if (t == 0) out[0] = v;
}

extern "C" void kernel_launch(void* const* d_in, const int* in_sizes, int n_in,
                              void* d_out, int out_size, void* d_ws, size_t ws_size,
                              hipStream_t stream)
{
    const float* em    = (const float*)d_in[0];   // [B,L,T] f32
    const int*   tgt   = (const int*)d_in[1];     // [B,L]
    const int*   mask  = (const int*)d_in[2];     // [B,L]
    const float* start = (const float*)d_in[3];   // [T]
    const float* endt  = (const float*)d_in[4];   // [T]
    const float* trans = (const float*)d_in[5];   // [T,T]
    float* out = (float*)d_out;

    float*    den    = (float*)d_ws;             // [64]
    float*    num    = den + BB;                 // [64]
    unsigned* okpart = (unsigned*)(den + 128);   // [64]
    float*    r      = den + 256;                // [NROWS]
    float*    etag   = r + NROWS;                // [NROWS]

    if (ws_size >= (size_t)WS_NEED) {
        crf_rowlse_kernel<<<NROWS / 8, 256, 0, stream>>>(em, tgt, trans, r, etag, okpart);
        crf_combine_kernel<<<BB, 256, 0, stream>>>(em, tgt, mask, start, endt, trans,
                                                   okpart, r, etag, den, num);
        crf_num_kernel<<<BB, 256, 0, stream>>>(em, tgt, mask, start, endt, trans, num, okpart);
        crf_forward_kernel<<<BB, 256, 0, stream>>>(em, mask, start, endt, trans, den, okpart);
        crf_final_kernel<<<1, 64, 0, stream>>>(den, num, out);
    } else {
        crf_num_kernel<<<BB, 256, 0, stream>>>(em, tgt, mask, start, endt, trans, num, nullptr);
        crf_forward_kernel<<<BB, 256, 0, stream>>>(em, mask, start, endt, trans, den, nullptr);
        crf_final_kernel<<<1, 64, 0, stream>>>(den, num, out);
    }
}

// Round 10
// 27.499 us; speedup vs baseline: 34.9164x; 1.1231x over previous
//
#include <hip/hip_runtime.h>

#define BB 64
#define LL 2048
#define TT 128
#define NROWS (BB * LL)

// ws layout (4B units): den[0..63] num[64..127] okpart[128..191] (u32)
//                       r[256 .. 256+NROWS) etag[256+NROWS .. 256+2*NROWS)
#define WS_NEED ((256 + 2 * NROWS) * 4)

// ---------------- fused: per-row lse + gold-tag gather + trans uniformity check ----
// 256 thr = 4 waves; wave = 2 rows (float4/lane). Blocks 0..63 also check a
// 256-entry slice of trans and write okpart[block].
__global__ __launch_bounds__(256) void crf_rowlse_kernel(
    const float* __restrict__ em, const int* __restrict__ tgt,
    const float* __restrict__ trans,
    float* __restrict__ r, float* __restrict__ etag,
    unsigned* __restrict__ okpart)
{
    const int t = threadIdx.x;
    const int wave = t >> 6, l = t & 63;
    const int h = l >> 5;                       // half-wave
    const int wv = blockIdx.x * 4 + wave;       // global wave id
    const int row = wv * 2 + h;                 // row handled by this half

    __shared__ int oksh[4];
    if (blockIdx.x < 64) {
        const unsigned t0b = __float_as_uint(trans[0]);
        const int ok = (__float_as_uint(trans[blockIdx.x * 256 + t]) == t0b);
        const int wok = __all(ok);
        if (l == 0) oksh[wave] = wok;
        __syncthreads();
        if (t == 0) okpart[blockIdx.x] = (unsigned)(oksh[0] & oksh[1] & oksh[2] & oksh[3]);
    }

    // row lse (float4: lanes 0-31 row, lanes 32-63 row+1)
    const float4 v = *(const float4*)(em + (size_t)wv * 256 + l * 4);
    float mx = fmaxf(fmaxf(v.x, v.y), fmaxf(v.z, v.w));
    #pragma unroll
    for (int off = 16; off; off >>= 1) mx = fmaxf(mx, __shfl_xor(mx, off));
    float s = __expf(v.x - mx) + __expf(v.y - mx) + __expf(v.z - mx) + __expf(v.w - mx);
    #pragma unroll
    for (int off = 16; off; off >>= 1) s += __shfl_xor(s, off);

    // gold-tag gather: etag[row] = em[row][tg]
    const int tg = tgt[row];                    // uniform within half-wave
    const float c01 = (tg & 1) ? v.y : v.x;
    const float c23 = (tg & 1) ? v.w : v.z;
    const float cand = (tg & 2) ? c23 : c01;
    const float ev = __shfl(cand, (h << 5) + (tg >> 2));

    if ((l & 31) == 0) {
        r[row] = mx + __logf(s);
        etag[row] = ev;
    }
}

// ---------------- per-batch: uniform-path combine OR general num+forward ---------
typedef float v4f __attribute__((ext_vector_type(4)));
__device__ __forceinline__ float rl(float v, int k) {
    return __uint_as_float((unsigned)__builtin_amdgcn_readlane((int)__float_as_uint(v), k));
}

__global__ __launch_bounds__(256, 1) __attribute__((amdgpu_waves_per_eu(1, 2)))
void crf_perbatch_kernel(
    const float* __restrict__ em, const int* __restrict__ tgt,
    const int* __restrict__ mask, const float* __restrict__ start,
    const float* __restrict__ endt, const float* __restrict__ trans,
    const unsigned* __restrict__ okpart, const float* __restrict__ r,
    const float* __restrict__ etag,
    float* __restrict__ den_out, float* __restrict__ num_out)
{
    const int b = blockIdx.x;
    const int t = threadIdx.x;
    const int w = t >> 6, l = t & 63;

    __shared__ int fsh[4];
    int uniform = 0;
    if (okpart) {
        const int myok = (t < 64) ? (int)okpart[t] : 1;
        const int wok = __all(myok);
        if (l == 0) fsh[w] = wok;
        __syncthreads();
        uniform = fsh[0] & fsh[1] & fsh[2] & fsh[3];
        __syncthreads();
    }

    const float* emb = em + (size_t)b * LL * TT;
    const int* mb = mask + (size_t)b * LL;

    if (uniform) {
        // ------- combine path: den_b and num_b in closed form -------
        const float* rb = r + (size_t)b * LL;
        const float* eb = etag + (size_t)b * LL;

        __shared__ float s_rs[4], s_es[4];
        __shared__ int s_k[4], s_last[4];
        __shared__ int g_k, g_last;
        __shared__ float g_rs, g_es;
        __shared__ float s_max[4], s_sum[4];

        int k = 0, last = 0;
        float rs = 0.f, es = 0.f;
        for (int i = t; i < LL; i += 256) {
            const int mv = (i >= 1) ? mb[i] : 0;
            if (mv > 0) { ++k; last = (i > last) ? i : last; rs += rb[i]; es += eb[i]; }
        }
        #pragma unroll
        for (int off = 32; off; off >>= 1) {
            k += __shfl_xor(k, off);
            last = max(last, __shfl_xor(last, off));
            rs += __shfl_xor(rs, off);
            es += __shfl_xor(es, off);
        }
        if (l == 0) { s_k[w] = k; s_last[w] = last; s_rs[w] = rs; s_es[w] = es; }
        __syncthreads();
        if (t == 0) {
            g_k = s_k[0] + s_k[1] + s_k[2] + s_k[3];
            g_last = max(max(s_last[0], s_last[1]), max(s_last[2], s_last[3]));
            g_rs = s_rs[0] + s_rs[1] + s_rs[2] + s_rs[3];
            g_es = s_es[0] + s_es[1] + s_es[2] + s_es[3];
        }
        __syncthreads();
        const int K = g_k;
        const int lastI = g_last;

        // waves 0,1: lse(start+em0 [+end if K==0]); waves 2,3: lse(em_last+end)
        float x;
        if (t < 128) {
            x = start[t] + emb[t] + ((K == 0) ? endt[t] : 0.f);
        } else {
            const int j = t - 128;
            x = (K > 0) ? (emb[(size_t)lastI * TT + j] + endt[j]) : -1e30f;
        }
        float mx = x;
        #pragma unroll
        for (int off = 32; off; off >>= 1) mx = fmaxf(mx, __shfl_xor(mx, off));
        if (l == 0) s_max[w] = mx;
        __syncthreads();
        const float m01 = fmaxf(s_max[0], s_max[1]);
        const float m23 = fmaxf(s_max[2], s_max[3]);
        float e = __expf(x - ((t < 128) ? m01 : m23));
        #pragma unroll
        for (int off = 32; off; off >>= 1) e += __shfl_xor(e, off);
        if (l == 0) s_sum[w] = e;
        __syncthreads();
        if (t == 0) {
            const float t0 = trans[0];
            const int tg0 = tgt[(size_t)b * LL];
            const float et0 = eb[0];
            const float lse0 = m01 + __logf(s_sum[0] + s_sum[1]);
            if (K == 0) {
                den_out[b] = lse0;
                num_out[b] = start[tg0] + et0 + endt[tg0];
            } else {
                const float lseE = m23 + __logf(s_sum[2] + s_sum[3]);
                den_out[b] = lse0 + (float)K * t0 + (g_rs - rb[lastI]) + lseE;
                const int tgl = tgt[(size_t)b * LL + K];   // seq_ends = sum(mask)-1 = K
                num_out[b] = start[tg0] + et0 + (float)K * t0 + g_es + endt[tgl];
            }
        }
        return;
    }

    // ------- general path: numerator, then forward scan (round-6 validated) -------
    {
        const int* tb = tgt + (size_t)b * LL;
        float acc = 0.f;
        int msum = 0;
        for (int x = t; x < LL; x += 256) {
            int mv = mb[x];
            msum += mv;
            if (x >= 1 && mv > 0) {
                int tp = tb[x - 1], tc = tb[x];
                acc += trans[tp * TT + tc] + emb[(size_t)x * TT + tc];
            }
        }
        __shared__ float sacc[4];
        __shared__ int smsum[4];
        #pragma unroll
        for (int off = 32; off; off >>= 1) {
            acc += __shfl_xor(acc, off);
            msum += __shfl_xor(msum, off);
        }
        if (l == 0) { sacc[w] = acc; smsum[w] = msum; }
        __syncthreads();
        if (t == 0) {
            float tot = sacc[0] + sacc[1] + sacc[2] + sacc[3];
            int total_mask = smsum[0] + smsum[1] + smsum[2] + smsum[3];
            int t0 = tb[0];
            tot += start[t0] + emb[t0];
            int se = total_mask - 1;
            int lt = tb[se];
            tot += endt[lt];
            num_out[b] = tot;
        }
        __syncthreads();
    }

    const int jr   = w & 1;
    const int tjr  = w >> 1;
    const int jown = (jr  << 6) + l;
    const int jtgt = (tjr << 6) + l;
    const int kbase = jr << 6;

    __shared__ float partial_sh[2][2][2][64];
    __shared__ float s0_sh[2];
    __shared__ int   mask_sh[LL];
    __shared__ float red[4], red2[4];

    for (int x = t; x < LL; x += 256) mask_sh[x] = mb[x];

    float cjE = -1e30f, cjS = -1e30f;
    for (int k = 0; k < TT; ++k) {
        cjE = fmaxf(cjE, trans[k * TT + jtgt]);
        cjS = fmaxf(cjS, trans[k * TT + jown]);
    }

#define EINIT(n) const v4f E##n = { \
    __expf(trans[(kbase + 4*(n) + 0) * TT + jtgt] - cjE), \
    __expf(trans[(kbase + 4*(n) + 1) * TT + jtgt] - cjE), \
    __expf(trans[(kbase + 4*(n) + 2) * TT + jtgt] - cjE), \
    __expf(trans[(kbase + 4*(n) + 3) * TT + jtgt] - cjE) };
    EINIT(0)  EINIT(1)  EINIT(2)  EINIT(3)
    EINIT(4)  EINIT(5)  EINIT(6)  EINIT(7)
    EINIT(8)  EINIT(9)  EINIT(10) EINIT(11)
    EINIT(12) EINIT(13) EINIT(14) EINIT(15)
#undef EINIT

    float s = start[jown] + emb[jown];
    if (t == 0) { s0_sh[0] = s; s0_sh[1] = s; }
    __syncthreads();
    float m_reg = s0_sh[0];

    float e0 = emb[(size_t)1 * TT + jown];
    float e1 = emb[(size_t)2 * TT + jown];
    float e2 = emb[(size_t)3 * TT + jown];
    float e3 = emb[(size_t)4 * TT + jown];
    float e4 = emb[(size_t)5 * TT + jown];
    float e5 = emb[(size_t)6 * TT + jown];
    float e6 = emb[(size_t)7 * TT + jown];
    float e7 = emb[(size_t)8 * TT + jown];

    for (int i = 1; i < LL; ++i) {
        const float em_cur = e0;
        e0 = e1; e1 = e2; e2 = e3; e3 = e4; e4 = e5; e5 = e6; e6 = e7;
        if (i + 8 < LL) e7 = emb[(size_t)(i + 8) * TT + jown];

        const float p = __expf(s - m_reg);

        float a0 = 0.f, a1 = 0.f, a2 = 0.f, a3 = 0.f;
#define FMA4(n) \
        a0 = fmaf(rl(p, 4*(n)+0), E##n.x, a0); \
        a1 = fmaf(rl(p, 4*(n)+1), E##n.y, a1); \
        a2 = fmaf(rl(p, 4*(n)+2), E##n.z, a2); \
        a3 = fmaf(rl(p, 4*(n)+3), E##n.w, a3);
        FMA4(0)  FMA4(1)  FMA4(2)  FMA4(3)
        FMA4(4)  FMA4(5)  FMA4(6)  FMA4(7)
        FMA4(8)  FMA4(9)  FMA4(10) FMA4(11)
        FMA4(12) FMA4(13) FMA4(14) FMA4(15)
#undef FMA4
        const float partial = (a0 + a2) + (a1 + a3);

        const int buf = i & 1;
        partial_sh[buf][tjr][jr][l] = partial;
        if (t == 0) s0_sh[buf] = s;

        asm volatile("s_waitcnt lgkmcnt(0)" ::: "memory");
        __builtin_amdgcn_s_barrier();
        asm volatile("" ::: "memory");

        const float pa = partial_sh[buf][jr][0][l];
        const float pb = partial_sh[buf][jr][1][l];
        const float mnext = s0_sh[buf];
        const float acc2 = pa + pb;

        const float snew = em_cur + m_reg + cjS + __logf(acc2);
        s = (mask_sh[i] > 0) ? snew : s;
        m_reg = mnext;
    }

    float v = s + endt[jown];
    float m2 = v;
    #pragma unroll
    for (int off = 32; off; off >>= 1) m2 = fmaxf(m2, __shfl_xor(m2, off));
    if (l == 0) red2[w] = m2;
    __syncthreads();
    m2 = fmaxf(fmaxf(red2[0], red2[1]), fmaxf(red2[2], red2[3]));
    float e = (w < 2) ? __expf(v - m2) : 0.f;
    #pragma unroll
    for (int off = 32; off; off >>= 1) e += __shfl_xor(e, off);
    if (l == 0) red[w] = e;
    __syncthreads();
    if (t == 0) den_out[b] = m2 + __logf(red[0] + red[1] + red[2] + red[3]);
}

// ---------------- final: out = sum_b (den_b - num_b) ----------------
__global__ void crf_final_kernel(const float* __restrict__ den,
                                 const float* __restrict__ num,
                                 float* __restrict__ out)
{
    int t = threadIdx.x;   // 64 threads == BB
    float v = den[t] - num[t];
    #pragma unroll
    for (int off = 32; off; off >>= 1) v += __shfl_xor(v, off);
    if (t == 0) out[0] = v;
}

extern "C" void kernel_launch(void* const* d_in, const int* in_sizes, int n_in,
                              void* d_out, int out_size, void* d_ws, size_t ws_size,
                              hipStream_t stream)
{
    const float* em    = (const float*)d_in[0];   // [B,L,T] f32
    const int*   tgt   = (const int*)d_in[1];     // [B,L]
    const int*   mask  = (const int*)d_in[2];     // [B,L]
    const float* start = (const float*)d_in[3];   // [T]
    const float* endt  = (const float*)d_in[4];   // [T]
    const float* trans = (const float*)d_in[5];   // [T,T]
    float* out = (float*)d_out;

    float*    den    = (float*)d_ws;             // [64]
    float*    num    = den + BB;                 // [64]
    unsigned* okpart = (unsigned*)(den + 128);   // [64]
    float*    r      = den + 256;                // [NROWS]
    float*    etag   = r + NROWS;                // [NROWS]

    if (ws_size >= (size_t)WS_NEED) {
        crf_rowlse_kernel<<<NROWS / 8, 256, 0, stream>>>(em, tgt, trans, r, etag, okpart);
        crf_perbatch_kernel<<<BB, 256, 0, stream>>>(em, tgt, mask, start, endt, trans,
                                                    okpart, r, etag, den, num);
        crf_final_kernel<<<1, 64, 0, stream>>>(den, num, out);
    } else {
        crf_perbatch_kernel<<<BB, 256, 0, stream>>>(em, tgt, mask, start, endt, trans,
                                                    nullptr, nullptr, nullptr, den, num);
        crf_final_kernel<<<1, 64, 0, stream>>>(den, num, out);
    }
}